// Round 1
// baseline (4040.683 us; speedup 1.0000x reference)
//
#include <hip/hip_runtime.h>

#define N_NODES 262144
#define N_EDGES 4194304
#define N_GRAPHS 1024
#define IN_DIM 10
#define HIDDEN 32

// ---- helpers ---------------------------------------------------------------

__device__ __forceinline__ float fatomic_add(float* p, float v) {
    // HW global_atomic_add_f32 (no CAS loop). Values are normal-range floats.
    return unsafeAtomicAdd(p, v);
}

// ---- degree / norm ----------------------------------------------------------

__global__ void deg_init(float* __restrict__ deg) {
    int i = blockIdx.x * blockDim.x + threadIdx.x;
    if (i < N_NODES) deg[i] = 1.0f;   // self-loop
}

__global__ void deg_edges(const int* __restrict__ dst, float* __restrict__ deg) {
    int e = blockIdx.x * blockDim.x + threadIdx.x;
    if (e < N_EDGES) fatomic_add(&deg[dst[e]], 1.0f);
}

__global__ void dinv_k(float* __restrict__ deg) {
    int i = blockIdx.x * blockDim.x + threadIdx.x;
    if (i < N_NODES) deg[i] = rsqrtf(deg[i]);   // deg >= 1 always
}

// ---- layer 1: h1s = (x @ W1) * dinv  ->  A ---------------------------------

__global__ void compute1(const float* __restrict__ x, const float* __restrict__ W1,
                         const float* __restrict__ dinv, float* __restrict__ A) {
    __shared__ float w[IN_DIM * HIDDEN];
    int t = threadIdx.x;
    for (int j = t; j < IN_DIM * HIDDEN; j += 256) w[j] = W1[j];
    __syncthreads();
    int tid = blockIdx.x * blockDim.x + t;
    int n = tid >> 5, c = tid & 31;
    if (n < N_NODES) {
        float s = 0.0f;
        #pragma unroll
        for (int k = 0; k < IN_DIM; ++k) s += x[n * IN_DIM + k] * w[k * HIDDEN + c];
        A[tid] = s * dinv[n];
    }
}

// ---- edge scatter: G[dst] += H[src]  (8 lanes per edge, float4 each) --------

__global__ void scatter_k(const int* __restrict__ src, const int* __restrict__ dst,
                          const float* __restrict__ H, float* __restrict__ G) {
    int t = blockIdx.x * blockDim.x + threadIdx.x;
    int e = t >> 3, q = t & 7;
    if (e < N_EDGES) {
        int s = src[e], d = dst[e];
        const float4 v = *reinterpret_cast<const float4*>(H + (size_t)s * HIDDEN + q * 4);
        float* g = G + (size_t)d * HIDDEN + q * 4;
        fatomic_add(g + 0, v.x);
        fatomic_add(g + 1, v.y);
        fatomic_add(g + 2, v.z);
        fatomic_add(g + 3, v.w);
    }
}

// ---- finalize layer 1: z = relu(dinv*(B + A) + b1) -> A ; B := 0 ------------

__global__ void finalize1(const float* __restrict__ dinv, const float* __restrict__ b1,
                          float* __restrict__ A, float* __restrict__ B) {
    int tid = blockIdx.x * blockDim.x + threadIdx.x;
    int n = tid >> 5, c = tid & 31;
    if (n < N_NODES) {
        float v = dinv[n] * (B[tid] + A[tid]) + b1[c];
        A[tid] = v > 0.0f ? v : 0.0f;
        B[tid] = 0.0f;
    }
}

// ---- layer 2: h2s = (z @ W2) * dinv -> A (in place, LDS-staged) -------------

__global__ void compute2(const float* __restrict__ W2, const float* __restrict__ dinv,
                         float* __restrict__ A) {
    __shared__ float w[HIDDEN * HIDDEN];
    __shared__ float zt[8][HIDDEN];
    int t = threadIdx.x;
    for (int j = t; j < HIDDEN * HIDDEN; j += 256) w[j] = W2[j];
    int tid = blockIdx.x * blockDim.x + t;
    int i = t >> 5, c = t & 31;
    int n = tid >> 5;
    zt[i][c] = A[tid];
    __syncthreads();
    float s = 0.0f;
    #pragma unroll
    for (int k = 0; k < HIDDEN; ++k) s += zt[i][k] * w[k * HIDDEN + c];
    A[tid] = s * dinv[n];
}

// ---- finalize layer 2 + mean-pool atomics -----------------------------------

__global__ void finalize2_pool(const float* __restrict__ dinv, const float* __restrict__ b2,
                               const int* __restrict__ batch,
                               const float* __restrict__ A, const float* __restrict__ B,
                               float* __restrict__ pooled, float* __restrict__ cnt) {
    int tid = blockIdx.x * blockDim.x + threadIdx.x;
    int n = tid >> 5, c = tid & 31;
    if (n < N_NODES) {
        float v = dinv[n] * (B[tid] + A[tid]) + b2[c];
        v = v > 0.0f ? v : 0.0f;
        int g = batch[n];
        fatomic_add(&pooled[g * HIDDEN + c], v);
        if (c == 0) fatomic_add(&cnt[g], 1.0f);
    }
}

// ---- final linear: out[g] = dot(pooled[g]/max(cnt,1), Wlin) + blin ----------

__global__ void final_k(const float* __restrict__ pooled, const float* __restrict__ cnt,
                        const float* __restrict__ Wlin, const float* __restrict__ blin,
                        float* __restrict__ out) {
    int g = blockIdx.x * blockDim.x + threadIdx.x;
    if (g < N_GRAPHS) {
        float s = 0.0f;
        #pragma unroll
        for (int c = 0; c < HIDDEN; ++c) s += pooled[g * HIDDEN + c] * Wlin[c];
        float cc = cnt[g];
        if (cc < 1.0f) cc = 1.0f;
        out[g] = s / cc + blin[0];
    }
}

// ---- launch -----------------------------------------------------------------

extern "C" void kernel_launch(void* const* d_in, const int* in_sizes, int n_in,
                              void* d_out, int out_size, void* d_ws, size_t ws_size,
                              hipStream_t stream) {
    const float* x     = (const float*)d_in[0];
    const int*   ei    = (const int*)d_in[1];   // [2, E] flattened: row0=src, row1=dst
    const int*   batch = (const int*)d_in[2];
    const float* W1    = (const float*)d_in[3];
    const float* b1    = (const float*)d_in[4];
    const float* W2    = (const float*)d_in[5];
    const float* b2    = (const float*)d_in[6];
    const float* Wlin  = (const float*)d_in[7];
    const float* blin  = (const float*)d_in[8];
    float* out = (float*)d_out;

    float* A      = (float*)d_ws;                    // N*32 floats (gather buf)
    float* B      = A + (size_t)N_NODES * HIDDEN;    // N*32 floats (scatter buf)
    float* pooled = B + (size_t)N_NODES * HIDDEN;    // G*32
    float* cnt    = pooled + (size_t)N_GRAPHS * HIDDEN; // G
    float* deg    = cnt + N_GRAPHS;                  // N (deg -> dinv in place)

    const int* src = ei;
    const int* dst = ei + N_EDGES;

    // zero scatter buffer + pooled + cnt (contiguous region)
    size_t zbytes = ((size_t)N_NODES * HIDDEN + (size_t)N_GRAPHS * HIDDEN + N_GRAPHS) * sizeof(float);
    hipMemsetAsync(B, 0, zbytes, stream);

    const int BT = 256;
    deg_init<<<(N_NODES + BT - 1) / BT, BT, 0, stream>>>(deg);
    deg_edges<<<(N_EDGES + BT - 1) / BT, BT, 0, stream>>>(dst, deg);
    dinv_k<<<(N_NODES + BT - 1) / BT, BT, 0, stream>>>(deg);

    int nthread_nodes = N_NODES * HIDDEN;            // 8.4M
    compute1<<<nthread_nodes / BT, BT, 0, stream>>>(x, W1, deg, A);
    scatter_k<<<(N_EDGES * 8) / BT, BT, 0, stream>>>(src, dst, A, B);
    finalize1<<<nthread_nodes / BT, BT, 0, stream>>>(deg, b1, A, B);

    compute2<<<nthread_nodes / BT, BT, 0, stream>>>(W2, deg, A);
    scatter_k<<<(N_EDGES * 8) / BT, BT, 0, stream>>>(src, dst, A, B);
    finalize2_pool<<<nthread_nodes / BT, BT, 0, stream>>>(deg, b2, batch, A, B, pooled, cnt);

    final_k<<<(N_GRAPHS + BT - 1) / BT, BT, 0, stream>>>(pooled, cnt, Wlin, blin, out);
}

// Round 2
// 1129.682 us; speedup vs baseline: 3.5768x; 3.5768x over previous
//
#include <hip/hip_runtime.h>

#define N_NODES 262144
#define N_EDGES 4194304
#define N_GRAPHS 1024
#define IN_DIM 10
#define HIDDEN 32

__device__ __forceinline__ float fatomic_add(float* p, float v) {
    return unsafeAtomicAdd(p, v);   // HW global_atomic_add_f32
}

// ---- CSR build: degree histogram ------------------------------------------

__global__ void deg_count(const int* __restrict__ dst, int* __restrict__ cnt) {
    int e = blockIdx.x * blockDim.x + threadIdx.x;
    if (e < N_EDGES) atomicAdd(&cnt[dst[e]], 1);
}

// ---- 3-kernel exclusive scan over cnt[262144] (1024 blocks x 256) ----------

__global__ void scan1(const int* __restrict__ cnt, int* __restrict__ tmp,
                      int* __restrict__ bsum) {
    __shared__ int s[256];
    int i = blockIdx.x * 256 + threadIdx.x;
    int v = cnt[i];
    s[threadIdx.x] = v;
    __syncthreads();
    #pragma unroll
    for (int off = 1; off < 256; off <<= 1) {
        int t = (threadIdx.x >= off) ? s[threadIdx.x - off] : 0;
        __syncthreads();
        s[threadIdx.x] += t;
        __syncthreads();
    }
    tmp[i] = s[threadIdx.x];                       // inclusive within block
    if (threadIdx.x == 255) bsum[blockIdx.x] = s[255];
}

__global__ void scan2(int* __restrict__ bsum) {    // 1 block, 1024 threads
    __shared__ int s[1024];
    int v = bsum[threadIdx.x];
    s[threadIdx.x] = v;
    __syncthreads();
    for (int off = 1; off < 1024; off <<= 1) {
        int t = (threadIdx.x >= off) ? s[threadIdx.x - off] : 0;
        __syncthreads();
        s[threadIdx.x] += t;
        __syncthreads();
    }
    bsum[threadIdx.x] = s[threadIdx.x] - v;        // exclusive
}

__global__ void scan3(const int* __restrict__ cnt, const int* __restrict__ tmp,
                      const int* __restrict__ bsum, int* __restrict__ rowptr,
                      int* __restrict__ cursor, float* __restrict__ dinv) {
    int i = blockIdx.x * 256 + threadIdx.x;
    int c = cnt[i];
    int excl = tmp[i] - c + bsum[i >> 8];
    rowptr[i] = excl;
    cursor[i] = excl;
    dinv[i] = rsqrtf(1.0f + (float)c);             // deg includes self-loop
    if (i == N_NODES - 1) rowptr[N_NODES] = N_EDGES;
}

__global__ void csr_fill(const int* __restrict__ src, const int* __restrict__ dst,
                         int* __restrict__ cursor, int* __restrict__ esrc) {
    int e = blockIdx.x * blockDim.x + threadIdx.x;
    if (e < N_EDGES) {
        int d = dst[e];
        int pos = atomicAdd(&cursor[d], 1);
        esrc[pos] = src[e];
    }
}

// ---- layer 1 dense: A = (x @ W1) * dinv -------------------------------------

__global__ void compute1(const float* __restrict__ x, const float* __restrict__ W1,
                         const float* __restrict__ dinv, float* __restrict__ A) {
    __shared__ float w[IN_DIM * HIDDEN];
    int t = threadIdx.x;
    for (int j = t; j < IN_DIM * HIDDEN; j += 256) w[j] = W1[j];
    __syncthreads();
    int tid = blockIdx.x * blockDim.x + t;
    int n = tid >> 5, c = tid & 31;
    float s = 0.0f;
    #pragma unroll
    for (int k = 0; k < IN_DIM; ++k) s += x[n * IN_DIM + k] * w[k * HIDDEN + c];
    A[tid] = s * dinv[n];
}

// ---- layer 2 dense: A = (B @ W2) * dinv -------------------------------------

__global__ void compute2(const float* __restrict__ B, const float* __restrict__ W2,
                         const float* __restrict__ dinv, float* __restrict__ A) {
    __shared__ float w[HIDDEN * HIDDEN];
    __shared__ float zt[8][HIDDEN];
    int t = threadIdx.x;
    for (int j = t; j < HIDDEN * HIDDEN; j += 256) w[j] = W2[j];
    int tid = blockIdx.x * blockDim.x + t;
    int i = t >> 5, c = t & 31;
    int n = tid >> 5;
    zt[i][c] = B[tid];
    __syncthreads();
    float s = 0.0f;
    #pragma unroll
    for (int k = 0; k < HIDDEN; ++k) s += zt[i][k] * w[k * HIDDEN + c];
    A[tid] = s * dinv[n];
}

// ---- CSR gather aggregate, layer 1: B = relu(dinv*(sum + self) + b1) --------
// 8 lanes per node, each owning one float4 of the 32-wide row.

__global__ void agg_relu(const float* __restrict__ H, const int* __restrict__ esrc,
                         const int* __restrict__ rowptr, const float* __restrict__ dinv,
                         const float* __restrict__ b, float* __restrict__ out) {
    int t = blockIdx.x * 256 + threadIdx.x;
    int n = t >> 3, q = t & 7;
    const float4* Hv = reinterpret_cast<const float4*>(H);
    float4 s = Hv[(size_t)n * 8 + q];              // self-loop term
    int beg = rowptr[n], end = rowptr[n + 1];
    for (int i = beg; i < end; ++i) {
        int si = esrc[i];
        float4 v = Hv[(size_t)si * 8 + q];
        s.x += v.x; s.y += v.y; s.z += v.z; s.w += v.w;
    }
    float dn = dinv[n];
    float4 bb = reinterpret_cast<const float4*>(b)[q];
    float4 z;
    z.x = fmaxf(dn * s.x + bb.x, 0.0f);
    z.y = fmaxf(dn * s.y + bb.y, 0.0f);
    z.z = fmaxf(dn * s.z + bb.z, 0.0f);
    z.w = fmaxf(dn * s.w + bb.w, 0.0f);
    reinterpret_cast<float4*>(out)[(size_t)n * 8 + q] = z;
}

// ---- CSR gather aggregate, layer 2 + mean-pool atomics ----------------------

__global__ void agg_pool(const float* __restrict__ H, const int* __restrict__ esrc,
                         const int* __restrict__ rowptr, const float* __restrict__ dinv,
                         const float* __restrict__ b, const int* __restrict__ batch,
                         float* __restrict__ pooled, float* __restrict__ cntp) {
    int t = blockIdx.x * 256 + threadIdx.x;
    int n = t >> 3, q = t & 7;
    const float4* Hv = reinterpret_cast<const float4*>(H);
    float4 s = Hv[(size_t)n * 8 + q];
    int beg = rowptr[n], end = rowptr[n + 1];
    for (int i = beg; i < end; ++i) {
        int si = esrc[i];
        float4 v = Hv[(size_t)si * 8 + q];
        s.x += v.x; s.y += v.y; s.z += v.z; s.w += v.w;
    }
    float dn = dinv[n];
    float4 bb = reinterpret_cast<const float4*>(b)[q];
    float4 z;
    z.x = fmaxf(dn * s.x + bb.x, 0.0f);
    z.y = fmaxf(dn * s.y + bb.y, 0.0f);
    z.z = fmaxf(dn * s.z + bb.z, 0.0f);
    z.w = fmaxf(dn * s.w + bb.w, 0.0f);
    int g = batch[n];
    float* p = pooled + (size_t)g * HIDDEN + q * 4;
    fatomic_add(p + 0, z.x);
    fatomic_add(p + 1, z.y);
    fatomic_add(p + 2, z.z);
    fatomic_add(p + 3, z.w);
    if (q == 0) fatomic_add(&cntp[g], 1.0f);
}

// ---- final linear ------------------------------------------------------------

__global__ void final_k(const float* __restrict__ pooled, const float* __restrict__ cntp,
                        const float* __restrict__ Wlin, const float* __restrict__ blin,
                        float* __restrict__ out) {
    int g = blockIdx.x * blockDim.x + threadIdx.x;
    if (g < N_GRAPHS) {
        float s = 0.0f;
        #pragma unroll
        for (int c = 0; c < HIDDEN; ++c) s += pooled[g * HIDDEN + c] * Wlin[c];
        float cc = cntp[g];
        if (cc < 1.0f) cc = 1.0f;
        out[g] = s / cc + blin[0];
    }
}

// ---- launch -------------------------------------------------------------------

extern "C" void kernel_launch(void* const* d_in, const int* in_sizes, int n_in,
                              void* d_out, int out_size, void* d_ws, size_t ws_size,
                              hipStream_t stream) {
    const float* x     = (const float*)d_in[0];
    const int*   ei    = (const int*)d_in[1];
    const int*   batch = (const int*)d_in[2];
    const float* W1    = (const float*)d_in[3];
    const float* b1    = (const float*)d_in[4];
    const float* W2    = (const float*)d_in[5];
    const float* b2    = (const float*)d_in[6];
    const float* Wlin  = (const float*)d_in[7];
    const float* blin  = (const float*)d_in[8];
    float* out = (float*)d_out;

    const int* src = ei;
    const int* dst = ei + N_EDGES;

    // workspace layout
    float* A      = (float*)d_ws;                      // N*32
    float* B      = A + (size_t)N_NODES * HIDDEN;      // N*32
    float* dinv   = B + (size_t)N_NODES * HIDDEN;      // N
    int*   rowptr = (int*)(dinv + N_NODES);            // N+1
    int*   cursor = rowptr + N_NODES + 1;              // N
    int*   esrc   = cursor + N_NODES;                  // E
    int*   tmp    = esrc + N_EDGES;                    // N (scan temp)
    int*   bsum   = tmp + N_NODES;                     // 1024
    int*   cnt    = bsum + 1024;                       // N  -- zeroed region start
    float* pooled = (float*)(cnt + N_NODES);           // G*32
    float* cntp   = pooled + (size_t)N_GRAPHS * HIDDEN;// G

    size_t zbytes = ((size_t)N_NODES + (size_t)N_GRAPHS * HIDDEN + N_GRAPHS) * sizeof(int);
    hipMemsetAsync(cnt, 0, zbytes, stream);

    const int BT = 256;
    const int EG = (N_EDGES + BT - 1) / BT;            // 16384

    deg_count<<<EG, BT, 0, stream>>>(dst, cnt);
    scan1<<<N_NODES / 256, 256, 0, stream>>>(cnt, tmp, bsum);
    scan2<<<1, 1024, 0, stream>>>(bsum);
    scan3<<<N_NODES / 256, 256, 0, stream>>>(cnt, tmp, bsum, rowptr, cursor, dinv);
    csr_fill<<<EG, BT, 0, stream>>>(src, dst, cursor, esrc);

    const int NG32 = N_NODES * HIDDEN / BT;            // 32768
    const int NG8  = N_NODES * 8 / BT;                 // 8192

    compute1<<<NG32, BT, 0, stream>>>(x, W1, dinv, A);
    agg_relu<<<NG8, BT, 0, stream>>>(A, esrc, rowptr, dinv, b1, B);
    compute2<<<NG32, BT, 0, stream>>>(B, W2, dinv, A);
    agg_pool<<<NG8, BT, 0, stream>>>(A, esrc, rowptr, dinv, b2, batch, pooled, cntp);

    final_k<<<(N_GRAPHS + BT - 1) / BT, BT, 0, stream>>>(pooled, cntp, Wlin, blin, out);
}

// Round 3
// 807.183 us; speedup vs baseline: 5.0059x; 1.3995x over previous
//
#include <hip/hip_runtime.h>

#define N_NODES 262144
#define N_EDGES 4194304
#define N_GRAPHS 1024
#define IN_DIM 10
#define HIDDEN 32

__device__ __forceinline__ float fatomic_add(float* p, float v) {
    return unsafeAtomicAdd(p, v);   // HW global_atomic_add_f32
}

// ---- CSR build: degree histogram ------------------------------------------

__global__ void deg_count(const int* __restrict__ dst, int* __restrict__ cnt) {
    int e = blockIdx.x * blockDim.x + threadIdx.x;
    if (e < N_EDGES) atomicAdd(&cnt[dst[e]], 1);
}

// ---- 3-kernel exclusive scan over cnt[262144] ------------------------------

__global__ void scan1(const int* __restrict__ cnt, int* __restrict__ tmp,
                      int* __restrict__ bsum) {
    __shared__ int s[256];
    int i = blockIdx.x * 256 + threadIdx.x;
    int v = cnt[i];
    s[threadIdx.x] = v;
    __syncthreads();
    #pragma unroll
    for (int off = 1; off < 256; off <<= 1) {
        int t = (threadIdx.x >= off) ? s[threadIdx.x - off] : 0;
        __syncthreads();
        s[threadIdx.x] += t;
        __syncthreads();
    }
    tmp[i] = s[threadIdx.x];
    if (threadIdx.x == 255) bsum[blockIdx.x] = s[255];
}

__global__ void scan2(int* __restrict__ bsum) {    // 1 block x 1024
    __shared__ int s[1024];
    int v = bsum[threadIdx.x];
    s[threadIdx.x] = v;
    __syncthreads();
    for (int off = 1; off < 1024; off <<= 1) {
        int t = (threadIdx.x >= off) ? s[threadIdx.x - off] : 0;
        __syncthreads();
        s[threadIdx.x] += t;
        __syncthreads();
    }
    bsum[threadIdx.x] = s[threadIdx.x] - v;
}

__global__ void scan3(const int* __restrict__ cnt, const int* __restrict__ tmp,
                      const int* __restrict__ bsum, int* __restrict__ rowptr,
                      int* __restrict__ cursor, float* __restrict__ dinv) {
    int i = blockIdx.x * 256 + threadIdx.x;
    int c = cnt[i];
    int excl = tmp[i] - c + bsum[i >> 8];
    rowptr[i] = excl;
    cursor[i] = excl;
    dinv[i] = rsqrtf(1.0f + (float)c);
    if (i == N_NODES - 1) rowptr[N_NODES] = N_EDGES;
}

__global__ void csr_fill(const int* __restrict__ src, const int* __restrict__ dst,
                         int* __restrict__ cursor, int* __restrict__ esrc) {
    int e = blockIdx.x * blockDim.x + threadIdx.x;
    if (e < N_EDGES) {
        int d = dst[e];
        int pos = atomicAdd(&cursor[d], 1);
        esrc[pos] = src[e];
    }
}

// ---- prescale: xs[n][0..11] = x[n][0..9]*dinv[n], pad 0 ---------------------

__global__ void prescale(const float* __restrict__ x, const float* __restrict__ dinv,
                         float* __restrict__ xs) {
    int j = blockIdx.x * 256 + threadIdx.x;     // over N*12
    int n = j / 12, k = j - n * 12;
    xs[j] = (k < IN_DIM) ? x[n * IN_DIM + k] * dinv[n] : 0.0f;
}

// ---- agg1: aggx[n] = xs[n] + sum_{e->n} xs[src]  (12 floats/node) -----------
// one wave per node: 16 edge-groups x 4 lanes (q<3 carry float4s of the row)

__global__ void agg1(const float* __restrict__ xs, const int* __restrict__ esrc,
                     const int* __restrict__ rowptr, float* __restrict__ aggx) {
    int lane = threadIdx.x & 63;
    int n = blockIdx.x * 4 + (threadIdx.x >> 6);
    int q = lane & 3, g = lane >> 2;            // q: float4 idx (0..2 active), g: 0..15
    const float4* Xv = reinterpret_cast<const float4*>(xs);
    float4 s = make_float4(0.f, 0.f, 0.f, 0.f);
    if (g == 0 && q < 3) s = Xv[(size_t)n * 3 + q];   // self-loop
    int beg = rowptr[n], end = rowptr[n + 1];
    if (q < 3) {
        for (int i = beg + g; i < end; i += 16) {
            int si = esrc[i];
            float4 v = Xv[(size_t)si * 3 + q];
            s.x += v.x; s.y += v.y; s.z += v.z; s.w += v.w;
        }
    }
    #pragma unroll
    for (int m = 4; m <= 32; m <<= 1) {
        s.x += __shfl_xor(s.x, m);
        s.y += __shfl_xor(s.y, m);
        s.z += __shfl_xor(s.z, m);
        s.w += __shfl_xor(s.w, m);
    }
    if (g == 0 && q < 3) reinterpret_cast<float4*>(aggx)[(size_t)n * 3 + q] = s;
}

// ---- dense1: zs = relu(dinv*(aggx @ W1) + b1) * dinv ------------------------

__global__ void dense1(const float* __restrict__ aggx, const float* __restrict__ W1,
                       const float* __restrict__ dinv, const float* __restrict__ b1,
                       float* __restrict__ zs) {
    __shared__ float w[IN_DIM * HIDDEN];
    __shared__ float zt[8][12];
    int t = threadIdx.x;
    for (int j = t; j < IN_DIM * HIDDEN; j += 256) w[j] = W1[j];
    int base = blockIdx.x * 8;
    if (t < 96) zt[t / 12][t % 12] = aggx[(size_t)base * 12 + t];
    __syncthreads();
    int i = t >> 5, c = t & 31;
    int n = base + i;
    float s = 0.0f;
    #pragma unroll
    for (int k = 0; k < IN_DIM; ++k) s += zt[i][k] * w[k * HIDDEN + c];
    float dn = dinv[n];
    zs[(size_t)n * HIDDEN + c] = fmaxf(dn * s + b1[c], 0.0f) * dn;
}

// ---- agg2: aggz[n] = zs[n] + sum_{e->n} zs[src]  (32 floats/node) -----------
// one wave per node: 8 edge-groups x 8 lanes

__global__ void agg2(const float* __restrict__ zs, const int* __restrict__ esrc,
                     const int* __restrict__ rowptr, float* __restrict__ aggz) {
    int lane = threadIdx.x & 63;
    int n = blockIdx.x * 4 + (threadIdx.x >> 6);
    int q = lane & 7, g = lane >> 3;
    const float4* Hv = reinterpret_cast<const float4*>(zs);
    float4 s = make_float4(0.f, 0.f, 0.f, 0.f);
    if (g == 0) s = Hv[(size_t)n * 8 + q];            // self-loop
    int beg = rowptr[n], end = rowptr[n + 1];
    for (int i = beg + g; i < end; i += 8) {
        int si = esrc[i];
        float4 v = Hv[(size_t)si * 8 + q];
        s.x += v.x; s.y += v.y; s.z += v.z; s.w += v.w;
    }
    #pragma unroll
    for (int m = 8; m <= 32; m <<= 1) {
        s.x += __shfl_xor(s.x, m);
        s.y += __shfl_xor(s.y, m);
        s.z += __shfl_xor(s.z, m);
        s.w += __shfl_xor(s.w, m);
    }
    if (g == 0) reinterpret_cast<float4*>(aggz)[(size_t)n * 8 + q] = s;
}

// ---- dense2 + pooled run-reduction ------------------------------------------

__global__ void dense2_pool(const float* __restrict__ aggz, const float* __restrict__ W2,
                            const float* __restrict__ dinv, const float* __restrict__ b2,
                            const int* __restrict__ batch, float* __restrict__ pooled) {
    __shared__ float w[HIDDEN * HIDDEN];
    __shared__ float zt[8][HIDDEN];
    __shared__ float vsh[8][HIDDEN + 1];
    __shared__ int bsh[8];
    int t = threadIdx.x;
    for (int j = t; j < HIDDEN * HIDDEN; j += 256) w[j] = W2[j];
    int base = blockIdx.x * 8;
    zt[t >> 5][t & 31] = aggz[(size_t)base * HIDDEN + t];
    if (t < 8) bsh[t] = batch[base + t];
    __syncthreads();
    int i = t >> 5, c = t & 31;
    int n = base + i;
    float s = 0.0f;
    #pragma unroll
    for (int k = 0; k < HIDDEN; ++k) s += zt[i][k] * w[k * HIDDEN + c];
    vsh[i][c] = fmaxf(dinv[n] * s + b2[c], 0.0f);
    __syncthreads();
    if (t < HIDDEN) {                       // column t: run-reduce over 8 nodes
        float run = vsh[0][t];
        int cur = bsh[0];
        #pragma unroll
        for (int j = 1; j < 8; ++j) {
            int bg = bsh[j];
            if (bg == cur) run += vsh[j][t];
            else {
                fatomic_add(&pooled[(size_t)cur * HIDDEN + t], run);
                run = vsh[j][t];
                cur = bg;
            }
        }
        fatomic_add(&pooled[(size_t)cur * HIDDEN + t], run);
    }
}

// ---- final linear (graph counts via binary search on sorted batch) ----------

__global__ void final_k(const float* __restrict__ pooled, const int* __restrict__ batch,
                        const float* __restrict__ Wlin, const float* __restrict__ blin,
                        float* __restrict__ out) {
    int g = blockIdx.x * blockDim.x + threadIdx.x;
    if (g < N_GRAPHS) {
        int lo = 0, hi = N_NODES;
        while (lo < hi) { int mid = (lo + hi) >> 1; if (batch[mid] < g) lo = mid + 1; else hi = mid; }
        int first = lo;
        lo = 0; hi = N_NODES;
        while (lo < hi) { int mid = (lo + hi) >> 1; if (batch[mid] <= g) lo = mid + 1; else hi = mid; }
        float cc = (float)(lo - first);
        if (cc < 1.0f) cc = 1.0f;
        float s = 0.0f;
        #pragma unroll
        for (int c = 0; c < HIDDEN; ++c) s += pooled[(size_t)g * HIDDEN + c] * Wlin[c];
        out[g] = s / cc + blin[0];
    }
}

// ---- launch -------------------------------------------------------------------

extern "C" void kernel_launch(void* const* d_in, const int* in_sizes, int n_in,
                              void* d_out, int out_size, void* d_ws, size_t ws_size,
                              hipStream_t stream) {
    const float* x     = (const float*)d_in[0];
    const int*   ei    = (const int*)d_in[1];
    const int*   batch = (const int*)d_in[2];
    const float* W1    = (const float*)d_in[3];
    const float* b1    = (const float*)d_in[4];
    const float* W2    = (const float*)d_in[5];
    const float* b2    = (const float*)d_in[6];
    const float* Wlin  = (const float*)d_in[7];
    const float* blin  = (const float*)d_in[8];
    float* out = (float*)d_out;

    const int* src = ei;
    const int* dst = ei + N_EDGES;

    const size_t N = N_NODES;
    // feature arena (64N floats) with lifetime-based overlay:
    //   zs   = F[0,32N)     (dense1 -> agg2)
    //   xs   = F[32N,44N)   (prescale -> agg1)
    //   aggx = F[44N,56N)   (agg1 -> dense1)
    //   aggz = F[32N,64N)   (agg2 -> dense2; clobbers dead xs/aggx)
    float* F      = (float*)d_ws;
    float* zs     = F;
    float* xs     = F + 32 * N;
    float* aggx   = F + 44 * N;
    float* aggz   = F + 32 * N;
    float* dinv   = F + 64 * N;                       // N
    int*   rowptr = (int*)(dinv + N);                 // N+1
    int*   cursor = rowptr + N + 1;                   // N
    int*   esrc   = cursor + N;                       // E = 16N
    int*   tmp    = esrc + N_EDGES;                   // N
    int*   bsum   = tmp + N;                          // 1024
    int*   cnt    = bsum + 1024;                      // N   -- zeroed region
    float* pooled = (float*)(cnt + N);                // G*32

    size_t zbytes = (N + (size_t)N_GRAPHS * HIDDEN) * sizeof(int);
    hipMemsetAsync(cnt, 0, zbytes, stream);

    const int BT = 256;
    const int EG = (N_EDGES + BT - 1) / BT;           // 16384

    deg_count<<<EG, BT, 0, stream>>>(dst, cnt);
    scan1<<<N_NODES / 256, 256, 0, stream>>>(cnt, tmp, bsum);
    scan2<<<1, 1024, 0, stream>>>(bsum);
    scan3<<<N_NODES / 256, 256, 0, stream>>>(cnt, tmp, bsum, rowptr, cursor, dinv);
    csr_fill<<<EG, BT, 0, stream>>>(src, dst, cursor, esrc);

    prescale<<<N_NODES * 12 / BT, BT, 0, stream>>>(x, dinv, xs);
    agg1<<<N_NODES / 4, BT, 0, stream>>>(xs, esrc, rowptr, aggx);
    dense1<<<N_NODES / 8, BT, 0, stream>>>(aggx, W1, dinv, b1, zs);
    agg2<<<N_NODES / 4, BT, 0, stream>>>(zs, esrc, rowptr, aggz);
    dense2_pool<<<N_NODES / 8, BT, 0, stream>>>(aggz, W2, dinv, b2, batch, pooled);

    final_k<<<(N_GRAPHS + BT - 1) / BT, BT, 0, stream>>>(pooled, batch, Wlin, blin, out);
}